// Round 9
// baseline (377.068 us; speedup 1.0000x reference)
//
#include <hip/hip_runtime.h>
#include <math.h>

#define D_MODEL 1024
#define NHEAD   16
#define HDIM    64
#define HID     2730
#define HID_PAD 2816          // 22 * 128
#define SEQ     2048
#define BATCH   2
#define NTOK    (BATCH * SEQ)   // 4096
#define QKG     3072            // packed q|k|g row stride (elements)

typedef __attribute__((ext_vector_type(8))) short bf16x8;
typedef __attribute__((ext_vector_type(4))) float f32x4;
typedef __attribute__((ext_vector_type(4))) short s16x4;

// fp32 -> bf16 round-to-nearest-even
static __device__ inline short f2bf(float f)
{
    union { float f; unsigned int u; } c; c.f = f;
    unsigned int r = c.u + 0x7FFFu + ((c.u >> 16) & 1u);
    return (short)(r >> 16);
}
static __device__ inline float bf2f(short s)
{
    union { unsigned int u; float f; } c;
    c.u = ((unsigned int)(unsigned short)s) << 16;
    return c.f;
}

// async global->LDS, 16B per lane; lds dest = wave-uniform base + lane*16
#define GLD16(gsrc, ldst) \
    __builtin_amdgcn_global_load_lds((const __attribute__((address_space(1))) void*)(gsrc), \
                                     (__attribute__((address_space(3))) void*)(ldst), 16, 0, 0)

// ---------------------------------------------------------------------------
// LDS bank-conflict-free tile layout (T2):
//   logical tile [R rows][32 k-shorts] stored as [R/2][64] where row r, granule
//   q (8 shorts) lives at p = r % (R/2), g = ((r / (R/2)) * 4 + q) ^ (p & 7).
//   Staging: LDS dest stays LINEAR; per-lane GLOBAL source is inverse-permuted.
// ---------------------------------------------------------------------------

// ---------------------------------------------------------------------------
// LayerNorm: one block (256 threads) per row of 1024, fp32 in -> bf16 out
// ---------------------------------------------------------------------------
__global__ void ln_kernel(const float* __restrict__ x,
                          const float* __restrict__ w,
                          const float* __restrict__ b,
                          short* __restrict__ out,
                          float eps)
{
    int row = blockIdx.x;
    int t = threadIdx.x;               // 0..255
    const float4* xr = (const float4*)(x + (size_t)row * D_MODEL);
    float4 v = xr[t];
    float s  = v.x + v.y + v.z + v.w;
    float sq = v.x * v.x + v.y * v.y + v.z * v.z + v.w * v.w;
#pragma unroll
    for (int off = 32; off > 0; off >>= 1) {
        s  += __shfl_xor(s, off);
        sq += __shfl_xor(sq, off);
    }
    __shared__ float ss[4], ssq[4];
    int wave = t >> 6;
    if ((t & 63) == 0) { ss[wave] = s; ssq[wave] = sq; }
    __syncthreads();
    s  = ss[0] + ss[1] + ss[2] + ss[3];
    sq = ssq[0] + ssq[1] + ssq[2] + ssq[3];
    float mu  = s * (1.0f / D_MODEL);
    float var = sq * (1.0f / D_MODEL) - mu * mu;
    float inv = rsqrtf(var + eps);
    float4 wv = ((const float4*)w)[t];
    float4 bv = ((const float4*)b)[t];
    s16x4 o;
    o.x = f2bf((v.x - mu) * inv * wv.x + bv.x);
    o.y = f2bf((v.y - mu) * inv * wv.y + bv.y);
    o.z = f2bf((v.z - mu) * inv * wv.z + bv.z);
    o.w = f2bf((v.w - mu) * inv * wv.w + bv.w);
    *(s16x4*)(out + (size_t)row * D_MODEL + 4 * t) = o;
}

// ---------------------------------------------------------------------------
// Transpose job table
// ---------------------------------------------------------------------------
struct TJob {
    const float* src;
    short* dst;
    int ldsrc, coloff, nvalid, kvalid, KPAD, NPAD;
};
struct TJobs { TJob j[8]; };

// ---------------------------------------------------------------------------
// prep_kernel: LN1 (blocks 0..NTOK-1) + ALL weight transposes (compact grid).
// ---------------------------------------------------------------------------
#define TRN_BLOCKS 3392

__global__ __launch_bounds__(256) void prep_kernel(
        const float* __restrict__ x,
        const float* __restrict__ ln1w,
        const float* __restrict__ ln1b,
        short* __restrict__ xn,
        TJobs jobs)
{
    __shared__ float tile[64][65];
    __shared__ float ss[4], ssq[4];
    int bid = blockIdx.x;
    int t = threadIdx.x;

    if (bid < NTOK) {
        // ---- LN1 row ----
        int row = bid;
        const float4* xr = (const float4*)(x + (size_t)row * D_MODEL);
        float4 v = xr[t];
        float s  = v.x + v.y + v.z + v.w;
        float sq = v.x * v.x + v.y * v.y + v.z * v.z + v.w * v.w;
#pragma unroll
        for (int off = 32; off > 0; off >>= 1) {
            s  += __shfl_xor(s, off);
            sq += __shfl_xor(sq, off);
        }
        int wave = t >> 6;
        if ((t & 63) == 0) { ss[wave] = s; ssq[wave] = sq; }
        __syncthreads();
        s  = ss[0] + ss[1] + ss[2] + ss[3];
        sq = ssq[0] + ssq[1] + ssq[2] + ssq[3];
        float mu  = s * (1.0f / D_MODEL);
        float var = sq * (1.0f / D_MODEL) - mu * mu;
        float inv = rsqrtf(var + 1e-5f);
        float4 wv = ((const float4*)ln1w)[t];
        float4 bv = ((const float4*)ln1b)[t];
        s16x4 o;
        o.x = f2bf((v.x - mu) * inv * wv.x + bv.x);
        o.y = f2bf((v.y - mu) * inv * wv.y + bv.y);
        o.z = f2bf((v.z - mu) * inv * wv.z + bv.z);
        o.w = f2bf((v.w - mu) * inv * wv.w + bv.w);
        *(s16x4*)(xn + (size_t)row * D_MODEL + 4 * t) = o;
        return;
    }

    // ---- transpose job ----
    int local = bid - NTOK;
    int jbi, kt, nt;
    if (local < 1280) {                 // jobs 0-4: 16x16
        jbi = local >> 8;
        int l = local & 255;
        kt = l & 15; nt = l >> 4;
    } else if (local < 2688) {          // jobs 5,6: 16k x 44n
        int l2 = local - 1280;
        jbi = 5 + (l2 >= 704 ? 1 : 0);
        int l3 = (l2 >= 704) ? l2 - 704 : l2;
        kt = l3 & 15; nt = l3 >> 4;
    } else {                            // job 7: 44k x 16n
        int l4 = local - 2688;
        jbi = 7;
        kt = l4 % 44; nt = l4 / 44;
    }
    TJob jb = jobs.j[jbi];
    int k0 = kt * 64, n0 = nt * 64;
    {
        int kk = t >> 2, np = (t & 3) << 4;
        int k = k0 + kk;
        bool kok = k < jb.kvalid;
        const float* srow = jb.src + (size_t)k * jb.ldsrc + jb.coloff + n0 + np;
#pragma unroll
        for (int i = 0; i < 16; ++i) {
            int n = n0 + np + i;
            tile[kk][np + i] = (kok && n < jb.nvalid) ? srow[i] : 0.0f;
        }
    }
    __syncthreads();
    {
        int nn = t >> 2, kp = (t & 3) << 4;
        short* drow = jb.dst + (size_t)(n0 + nn) * jb.KPAD + k0 + kp;
#pragma unroll
        for (int v4 = 0; v4 < 4; ++v4) {
            s16x4 o;
            o.x = f2bf(tile[kp + v4 * 4 + 0][nn]);
            o.y = f2bf(tile[kp + v4 * 4 + 1][nn]);
            o.z = f2bf(tile[kp + v4 * 4 + 2][nn]);
            o.w = f2bf(tile[kp + v4 * 4 + 3][nn]);
            *(s16x4*)(drow + v4 * 4) = o;
        }
    }
}

// ---------------------------------------------------------------------------
// proj v3: 256 rows x 128 out-cols per block, 4 waves, wave-tile 128x64,
// BK=32 dbuf gload_lds, T2-swizzled LDS. 512 blocks = 2/CU, balanced.
// ---------------------------------------------------------------------------
__global__ __launch_bounds__(256, 2) void proj_kernel(
        const short* __restrict__ xn,
        const short* __restrict__ qkgT,
        short* __restrict__ qkg,
        const short* __restrict__ wvT,
        short* __restrict__ vT)
{
    __shared__ short As[2][8192];          // 256 r x 32 k (swizzled)
    __shared__ short Bs[2][4096];          // 128 n x 32 k (swizzled)
    const int K = D_MODEL;
    int id = blockIdx.x;
    const short *A, *Bt;
    short* C;
    int ldc, bm, bn;
    if (id < 384) {                        // xn @ qkgT^T -> qkg
        A = xn; Bt = qkgT; C = qkg; ldc = QKG;
        bm = (id & 15) * 256; bn = (id >> 4) * 128;
    } else {                               // wvT @ xn^T -> vT
        int i2 = id - 384;
        A = wvT; Bt = xn; C = vT; ldc = NTOK;
        bm = (i2 & 3) * 256; bn = (i2 >> 2) * 128;
    }

    int t = threadIdx.x;
    int w = t >> 6;
    int lane = t & 63;
    int quad = lane >> 4;
    int l15  = lane & 15;
    int x7   = l15 & 7;

    int li3 = lane >> 3;
    int u   = (lane & 7) ^ li3;
    int hi  = u >> 2;
    int qk  = (u & 3) << 3;
    const short* gA = A + (size_t)(bm + hi * 128 + w * 32 + li3) * K + qk;
    const short* gB = Bt + (size_t)(bn + hi * 64 + w * 16 + li3) * K + qk;

    int abase = l15 * 64 + ((((w >> 1) << 2) | quad) ^ x7) * 8;
    int bbase = l15 * 64 + ((((w & 1) << 2) | quad) ^ x7) * 8;

    f32x4 acc[8][4];
#pragma unroll
    for (int i = 0; i < 8; ++i)
#pragma unroll
        for (int j = 0; j < 4; ++j) acc[i][j] = (f32x4){0.f, 0.f, 0.f, 0.f};

#pragma unroll
    for (int c = 0; c < 4; ++c)
        GLD16(gA + (size_t)c * 8 * K, &As[0][w * 2048 + c * 512]);
#pragma unroll
    for (int c = 0; c < 2; ++c)
        GLD16(gB + (size_t)c * 8 * K, &Bs[0][w * 1024 + c * 512]);

    for (int k0 = 0; k0 < K; k0 += 32) {
        int cur = (k0 >> 5) & 1;
        __syncthreads();
        int k1 = k0 + 32;
        if (k1 < K) {
#pragma unroll
            for (int c = 0; c < 4; ++c)
                GLD16(gA + (size_t)c * 8 * K + k1, &As[cur ^ 1][w * 2048 + c * 512]);
#pragma unroll
            for (int c = 0; c < 2; ++c)
                GLD16(gB + (size_t)c * 8 * K + k1, &Bs[cur ^ 1][w * 1024 + c * 512]);
        }
        bf16x8 af[8], bfr[4];
#pragma unroll
        for (int m = 0; m < 8; ++m)
            af[m] = *(const bf16x8*)(&As[cur][m * 1024 + abase]);
#pragma unroll
        for (int jf = 0; jf < 4; ++jf)
            bfr[jf] = *(const bf16x8*)(&Bs[cur][jf * 1024 + bbase]);
#pragma unroll
        for (int m = 0; m < 8; ++m)
#pragma unroll
            for (int jf = 0; jf < 4; ++jf)
                acc[m][jf] = __builtin_amdgcn_mfma_f32_16x16x32_bf16(af[m], bfr[jf], acc[m][jf], 0, 0, 0);
    }

#pragma unroll
    for (int m = 0; m < 8; ++m) {
        int gr = bm + (w >> 1) * 128 + m * 16 + quad * 4;
#pragma unroll
        for (int jf = 0; jf < 4; ++jf) {
            int gc = bn + (w & 1) * 64 + jf * 16 + l15;
#pragma unroll
            for (int r = 0; r < 4; ++r)
                C[(size_t)(gr + r) * ldc + gc] = f2bf(acc[m][jf][r]);
        }
    }
}

// ---------------------------------------------------------------------------
// 128x64-tile GEMM for the N=1024 projections (wo, w_out): 512 blocks
// co-resident (4/CU); T2-swizzled LDS.
// ---------------------------------------------------------------------------
template<int EPI>
__global__ __launch_bounds__(256, 4) void gemm_n64(
        const short* __restrict__ A, int lda,
        const short* __restrict__ Bt,
        const float* __restrict__ bias,
        const float* __restrict__ R, int ldr,
        void* __restrict__ C, int ldc, int K)
{
    __shared__ short As[2][4096];
    __shared__ short Bs[2][2048];
    int bm = blockIdx.x * 128;          // row tile fastest
    int bn = blockIdx.y * 64;
    int t = threadIdx.x;
    int w = t >> 6;
    int lane = t & 63;
    int quad = lane >> 4;
    int l15  = lane & 15;
    int x7   = l15 & 7;

    int p0 = t >> 3;
    int u  = (t & 7) ^ (p0 & 7);
    int scol = (u & 3) << 3;
    const short* gA0 = A  + (size_t)(bm + p0 + ((u >> 2) << 6)) * lda + scol;
    const short* gA1 = gA0 + (size_t)32 * lda;
    const short* gB0 = Bt + (size_t)(bn + p0 + ((u >> 2) << 5)) * K + scol;  // 64-row tile: hi<<5
    int wb = w << 9;

    int wr = (w >> 1) * 64;
    int wc = (w & 1) * 32;
    int aoff = l15 * 64 + (((((w >> 1) << 2) | quad) ^ x7) << 3);
    int boff = l15 * 64 + (((((w & 1) << 2) | quad) ^ x7) << 3);

    f32x4 acc[4][2];
#pragma unroll
    for (int i = 0; i < 4; ++i)
#pragma unroll
        for (int j = 0; j < 2; ++j) acc[i][j] = (f32x4){0.f, 0.f, 0.f, 0.f};

    GLD16(gA0, &As[0][wb]);
    GLD16(gA1, &As[0][2048 + wb]);
    GLD16(gB0, &Bs[0][wb]);

    for (int k0 = 0; k0 < K; k0 += 32) {
        int cur = (k0 >> 5) & 1;
        __syncthreads();
        int k1 = k0 + 32;
        if (k1 < K) {
            GLD16(gA0 + k1, &As[cur ^ 1][wb]);
            GLD16(gA1 + k1, &As[cur ^ 1][2048 + wb]);
            GLD16(gB0 + k1, &Bs[cur ^ 1][wb]);
        }
        bf16x8 af[4], bfr[2];
#pragma unroll
        for (int i = 0; i < 4; ++i)
            af[i] = *(const bf16x8*)(&As[cur][i * 1024 + aoff]);
#pragma unroll
        for (int j = 0; j < 2; ++j)
            bfr[j] = *(const bf16x8*)(&Bs[cur][j * 1024 + boff]);
#pragma unroll
        for (int i = 0; i < 4; ++i)
#pragma unroll
            for (int j = 0; j < 2; ++j)
                acc[i][j] = __builtin_amdgcn_mfma_f32_16x16x32_bf16(af[i], bfr[j], acc[i][j], 0, 0, 0);
    }

#pragma unroll
    for (int i = 0; i < 4; ++i) {
        int gr = bm + wr + i * 16 + quad * 4;
#pragma unroll
        for (int j = 0; j < 2; ++j) {
            int gc = bn + wc + j * 16 + l15;
#pragma unroll
            for (int r = 0; r < 4; ++r) {
                float val = acc[i][j][r];
                size_t idx = (size_t)(gr + r) * ldc + gc;
                if (EPI == 0) {
                    ((short*)C)[idx] = f2bf(val);
                } else if (EPI == 1) {
                    ((float*)C)[idx] = val + R[(size_t)(gr + r) * ldr + gc];
                } else {
                    ((float*)C)[idx] = val + bias[gc] + R[(size_t)(gr + r) * ldr + gc];
                }
            }
        }
    }
}

// ---------------------------------------------------------------------------
// Fused SwiGLU-in GEMM v3: block 256 rows x 64 out-cols (128 a|b-interleaved
// weight rows), 4 waves with 128x64 wave-tiles, BK=32, 2-phase dbuf
// gload_lds, T2-swizzled LDS. Row-tile-fastest grid (proven fastest, r5).
// 2 blocks/CU (register-limited: 84 VGPR + 128 acc-AGPR, unified file).
// ---------------------------------------------------------------------------
__global__ __launch_bounds__(256, 2) void mlp_fused(
        const short* __restrict__ A,       // [NTOK][1024] bf16
        const short* __restrict__ w_inT,   // [2*HID_PAD][1024] bf16
        const float* __restrict__ b_in,    // [2*HID]
        short* __restrict__ hm)            // [NTOK][HID_PAD] bf16
{
    __shared__ short As[2][8192];          // 32 KB
    __shared__ short Bs[2][4096];          // 16 KB
    const int K = D_MODEL;
    int bm = blockIdx.x * 256;             // row tile fastest (16)
    int bn = blockIdx.y * 64;              // out-col tile (44)
    int t = threadIdx.x;
    int w = t >> 6;
    int lane = t & 63;
    int quad = lane >> 4;
    int l15  = lane & 15;
    int x7   = l15 & 7;

    int li3 = lane >> 3;
    int u   = (lane & 7) ^ li3;
    int hi  = u >> 2;
    int qk  = (u & 3) << 3;
    const short* gA = A + (size_t)(bm + hi * 128 + w * 32 + li3) * K + qk;
    int f = hi * 4 + w;
    const short* gB = w_inT + (size_t)(((f & 1) ? HID_PAD : 0) + bn
                                       + ((f >> 1) << 4) + li3) * K + qk;

    int abase = l15 * 64 + ((((w >> 1) << 2) | quad) ^ x7) * 8;
    int bbase = l15 * 64 + ((((w & 1) << 2) | quad) ^ x7) * 8;

    f32x4 acc[8][4];
#pragma unroll
    for (int i = 0; i < 8; ++i)
#pragma unroll
        for (int j = 0; j < 4; ++j) acc[i][j] = (f32x4){0.f, 0.f, 0.f, 0.f};

#pragma unroll
    for (int c = 0; c < 4; ++c)
        GLD16(gA + (size_t)c * 8 * K, &As[0][w * 2048 + c * 512]);
#pragma unroll
    for (int c = 0; c < 2; ++c)
        GLD16(gB + (size_t)c * 8 * K, &Bs[0][w * 1024 + c * 512]);

    for (int k0 = 0; k0 < K; k0 += 32) {
        int cur = (k0 >> 5) & 1;
        __syncthreads();
        int k1 = k0 + 32;
        if (k1 < K) {
#pragma unroll
            for (int c = 0; c < 4; ++c)
                GLD16(gA + (size_t)c * 8 * K + k1, &As[cur ^ 1][w * 2048 + c * 512]);
#pragma unroll
            for (int c = 0; c < 2; ++c)
                GLD16(gB + (size_t)c * 8 * K + k1, &Bs[cur ^ 1][w * 1024 + c * 512]);
        }
        bf16x8 af[8], bfr[4];
#pragma unroll
        for (int m = 0; m < 8; ++m)
            af[m] = *(const bf16x8*)(&As[cur][m * 1024 + abase]);
#pragma unroll
        for (int jf = 0; jf < 4; ++jf)
            bfr[jf] = *(const bf16x8*)(&Bs[cur][jf * 1024 + bbase]);
#pragma unroll
        for (int m = 0; m < 8; ++m)
#pragma unroll
            for (int jf = 0; jf < 4; ++jf)
                acc[m][jf] = __builtin_amdgcn_mfma_f32_16x16x32_bf16(af[m], bfr[jf], acc[m][jf], 0, 0, 0);
    }

#pragma unroll
    for (int m = 0; m < 8; ++m) {
        int gr = bm + (w >> 1) * 128 + m * 16 + quad * 4;
#pragma unroll
        for (int jj = 0; jj < 2; ++jj) {
            int gc = bn + (((w & 1) << 1) + jj) * 16 + l15;
            bool ok = gc < HID;
            float ba = ok ? b_in[gc] : 0.0f;
            float bb = ok ? b_in[HID + gc] : 0.0f;
#pragma unroll
            for (int r = 0; r < 4; ++r) {
                float a  = acc[m][2 * jj][r] + ba;
                float bv = acc[m][2 * jj + 1][r] + bb;
                float val = ok ? a * (bv / (1.0f + expf(-bv))) : 0.0f;
                hm[(size_t)(gr + r) * HID_PAD + gc] = f2bf(val);
            }
        }
    }
}

// ---------------------------------------------------------------------------
// MFMA retention + groupnorm + silu gate, v3:
//   - 64-row q-blocks: grid 1024 x 256 threads (4 waves x 16 rows).
//   - P stored per 32-token HALF (ps 16x36/wave): LDS 37.4KB -> 4 blocks/CU,
//     all 1024 blocks co-resident, 4 independent barrier groups/CU (was 2).
//   - balance: j = b ? m : 31-m  -> the 4 round-robin co-residents per CU
//     have j summing to 62 (constant 66 K-tiles/CU).
//   - numerics identical to the proven r7 kernel (same f2bf, rf recurrence).
// ---------------------------------------------------------------------------
#define PSH 36   // half-P row stride in shorts (>=32, bank-spread)

__global__ __launch_bounds__(256) void retention_mfma(
        const short* __restrict__ qkg,
        const short* __restrict__ vT,
        short* __restrict__ rg)
{
    int i  = blockIdx.x;                 // 0..1023
    int h  = i & 15;
    int t5 = i >> 4;                     // 0..63
    int b  = t5 >> 5;
    int m  = t5 & 31;
    int j  = b ? m : 31 - m;             // 64-row q-block index (0..31)

    __shared__ short ks[2][4096];        // [buf][d-chunk(2)][32][64] swizzled
    __shared__ short vt[2][4096];        // [buf][t-chunk(2)][32][64] swizzled
    __shared__ short ps[4][16 * PSH];    // per-wave HALF P (16 q x 32 t)

    int tid  = threadIdx.x;
    int w    = tid >> 6;                 // 0..3
    int lane = tid & 63;
    int quad = lane >> 4;
    int l15  = lane & 15;
    int x7   = l15 & 7;

    float log2g = log1pf(-exp2f(-5.0f - (float)h)) * 1.4426950408889634f;
    int hcol = h * HDIM;
    int s0 = j * 64;
    size_t tok0 = (size_t)b * SEQ;

    // swizzled staging source: dest slot (p = tid>>3, g = tid&7); chunk explicit
    int p0 = tid >> 3;                   // 0..31
    int g  = tid & 7;
    int ur = g ^ (p0 & 7);
    int srw = p0 + ((ur >> 2) << 5);     // row within 64-row tile
    int sc8 = (ur & 3) << 3;
    const short* kbase = qkg + (tok0 + srw) * QKG + 1024 + hcol + sc8;
    const short* vbase = vT + (size_t)(hcol + srw) * NTOK + tok0 + sc8;
    int lb = tid << 3;                   // 0..2047 (shorts within chunk)

    const short* qrow = qkg + (tok0 + s0 + w * 16 + l15) * QKG + hcol;
    bf16x8 qa0 = *(const bf16x8*)(qrow + quad * 8);
    bf16x8 qa1 = *(const bf16x8*)(qrow + 32 + quad * 8);

    float colfac[4];
#pragma unroll
    for (int tile = 0; tile < 4; ++tile)
        colfac[tile] = exp2f(-(float)(tile * 16 + l15) * log2g) * 0.125f;

    f32x4 oacc[4];
#pragma unroll
    for (int k = 0; k < 4; ++k) oacc[k] = (f32x4){0.f, 0.f, 0.f, 0.f};

    int sbase = s0 + w * 16 + quad * 4;
    int tmax = j;                        // tiles 0..j

    // row decay recurrence (proven r7): rf0 = gamma^(sbase+reg), *= gamma^-64
    float rf[4];
#pragma unroll
    for (int reg = 0; reg < 4; ++reg)
        rf[reg] = exp2f((float)(sbase + reg) * log2g);
    float gstep = exp2f(-64.0f * log2g);

    GLD16(kbase,      &ks[0][lb]);
    GLD16(kbase + 32, &ks[0][2048 + lb]);
    GLD16(vbase,      &vt[0][lb]);
    GLD16(vbase + 32, &vt[0][2048 + lb]);

    for (int tb = 0; tb <= tmax; ++tb) {
        int cur = tb & 1;
        __syncthreads();
        if (tb < tmax) {
            size_t ko = (size_t)(tb + 1) * 64 * QKG;
            int    vo = (tb + 1) * 64;
            GLD16(kbase + ko,      &ks[cur ^ 1][lb]);
            GLD16(kbase + ko + 32, &ks[cur ^ 1][2048 + lb]);
            GLD16(vbase + vo,      &vt[cur ^ 1][lb]);
            GLD16(vbase + vo + 32, &vt[cur ^ 1][2048 + lb]);
        }

        f32x4 sacc[4];
#pragma unroll
        for (int k = 0; k < 4; ++k) sacc[k] = (f32x4){0.f, 0.f, 0.f, 0.f};
#pragma unroll
        for (int tile = 0; tile < 4; ++tile) {
            int kaddr = ((tile & 1) * 16 + l15) * 64 +
                        (((((tile >> 1) << 2) | quad) ^ x7) << 3);
            bf16x8 kb0 = *(const bf16x8*)(&ks[cur][kaddr]);
            bf16x8 kb1 = *(const bf16x8*)(&ks[cur][2048 + kaddr]);
            sacc[tile] = __builtin_amdgcn_mfma_f32_16x16x32_bf16(qa0, kb0, sacc[tile], 0, 0, 0);
            sacc[tile] = __builtin_amdgcn_mfma_f32_16x16x32_bf16(qa1, kb1, sacc[tile], 0, 0, 0);
        }

        int fbi = sbase - tb * 64;
        bool needmask = (tb * 64 + 63 > s0 + w * 16);

#pragma unroll
        for (int ksi = 0; ksi < 2; ++ksi) {
            // ---- store half-P (tiles 2ksi, 2ksi+1) ----
            if (needmask) {
#pragma unroll
                for (int th = 0; th < 2; ++th) {
                    int tile = ksi * 2 + th;
                    int tt = tile * 16 + l15;
#pragma unroll
                    for (int reg = 0; reg < 4; ++reg) {
                        float p = (fbi + reg >= tt) ? sacc[tile][reg] * rf[reg] * colfac[tile] : 0.0f;
                        ps[w][(quad * 4 + reg) * PSH + th * 16 + l15] = f2bf(p);
                    }
                }
            } else {
#pragma unroll
                for (int th = 0; th < 2; ++th) {
                    int tile = ksi * 2 + th;
#pragma unroll
                    for (int reg = 0; reg < 4; ++reg)
                        ps[w][(quad * 4 + reg) * PSH + th * 16 + l15] =
                            f2bf(sacc[tile][reg] * (rf[reg] * colfac[tile]));
                }
            }
            // ---- PV with this half (wave-local LDS, in-order per wave) ----
            bf16x8 pa = *(const bf16x8*)(&ps[w][l15 * PSH + quad * 8]);
#pragma unroll
            for (int dt = 0; dt < 4; ++dt) {
                int vaddr = ((dt & 1) * 16 + l15) * 64 +
                            (((((dt >> 1) << 2) | quad) ^ x7) << 3);
                bf16x8 vb = *(const bf16x8*)(&vt[cur][ksi * 2048 + vaddr]);
                oacc[dt] = __builtin_amdgcn_mfma_f32_16x16x32_bf16(pa, vb, oacc[dt], 0, 0, 0);
            }
        }
#pragma unroll
        for (int reg = 0; reg < 4; ++reg)
            rf[reg] *= gstep;
    }

    float s1[4], s2[4];
#pragma unroll
    for (int reg = 0; reg < 4; ++reg) {
        s1[reg] = oacc[0][reg] + oacc[1][reg] + oacc[2][reg] + oacc[3][reg];
        s2[reg] = oacc[0][reg] * oacc[0][reg] + oacc[1][reg] * oacc[1][reg]
                + oacc[2][reg] * oacc[2][reg] + oacc[3][reg] * oacc[3][reg];
    }
#pragma unroll
    for (int off = 1; off < 16; off <<= 1) {
#pragma unroll
        for (int reg = 0; reg < 4; ++reg) {
            s1[reg] += __shfl_xor(s1[reg], off);
            s2[reg] += __shfl_xor(s2[reg], off);
        }
    }
    size_t rowtok = tok0 + s0 + w * 16 + quad * 4;
    short* obase = rg + rowtok * D_MODEL + hcol;
    const short* gbase = qkg + rowtok * QKG + 2048 + hcol;
#pragma unroll
    for (int reg = 0; reg < 4; ++reg) {
        float mu  = s1[reg] * (1.0f / 64.0f);
        float var = s2[reg] * (1.0f / 64.0f) - mu * mu;
        float inv = rsqrtf(var + 1e-6f);
#pragma unroll
        for (int dt = 0; dt < 4; ++dt) {
            float gv = bf2f(gbase[(size_t)reg * QKG + dt * 16 + l15]);
            float val = (oacc[dt][reg] - mu) * inv * (gv / (1.0f + expf(-gv)));
            obase[(size_t)reg * D_MODEL + dt * 16 + l15] = f2bf(val);
        }
    }
}

// ---------------------------------------------------------------------------
extern "C" void kernel_launch(void* const* d_in, const int* in_sizes, int n_in,
                              void* d_out, int out_size, void* d_ws, size_t ws_size,
                              hipStream_t stream)
{
    const float* x     = (const float*)d_in[0];
    const float* ln1w  = (const float*)d_in[1];
    const float* ln1b  = (const float*)d_in[2];
    const float* wq    = (const float*)d_in[3];
    const float* wk    = (const float*)d_in[4];
    const float* wv    = (const float*)d_in[5];
    const float* wg    = (const float*)d_in[6];
    const float* wo    = (const float*)d_in[7];
    const float* ln2w  = (const float*)d_in[8];
    const float* ln2b  = (const float*)d_in[9];
    const float* w_in  = (const float*)d_in[10];
    const float* b_in  = (const float*)d_in[11];
    const float* w_out = (const float*)d_in[12];
    const float* b_out = (const float*)d_in[13];
    float* out = (float*)d_out;
    char* base = (char*)d_ws;

    const size_t MB = 1u << 20;
    short* xn     = (short*)(base);            // [0,8)   [4096][1024] bf16 LN out
    short* qkgT   = (short*)(base +  8 * MB);  // [8,14)  wq|wk|wg transposed [3072][1024]
    short* wvT    = (short*)(base + 14 * MB);  // [14,16) [1024][1024]
    short* woT    = (short*)(base + 16 * MB);  // [16,18) [1024][1024]
    short* w_inT  = (short*)(base + 18 * MB);  // [18,29) [5632][1024]
    short* w_outT = (short*)(base + 29 * MB);  // [29,34.5) [1024][2816]
    short* qkg    = (short*)(base + 35 * MB);  // [35,59) [4096][3072] packed q|k|g
    short* hm     = (short*)(base + 35 * MB);  // [35,57) [4096][2816] reuses dead qkg
    short* vT     = (short*)(base + 59 * MB);  // [59,67) [1024][4096] V transposed
    short* rg     = (short*)(base + 67 * MB);  // [67,75) [4096][1024] gated retention out

    TJobs jobs;
    jobs.j[0] = { wq,    qkgT,                          1024,    0, 1024, 1024, 1024, 1024 };
    jobs.j[1] = { wk,    qkgT + 1024 * 1024,            1024,    0, 1024, 1024, 1024, 1024 };
    jobs.j[2] = { wg,    qkgT + 2 * 1024 * 1024,        1024,    0, 1024, 1024, 1024, 1024 };
    jobs.j[3] = { wv,    wvT,                           1024,    0, 1024, 1024, 1024, 1024 };
    jobs.j[4] = { wo,    woT,                           1024,    0, 1024, 1024, 1024, 1024 };
    jobs.j[5] = { w_in,  w_inT,                         2 * HID, 0,   HID, 1024, 1024, HID_PAD };
    jobs.j[6] = { w_in,  w_inT + (size_t)HID_PAD * 1024, 2 * HID, HID, HID, 1024, 1024, HID_PAD };
    jobs.j[7] = { w_out, w_outT,                        1024,    0, 1024, HID, HID_PAD, 1024 };

    // LN1 + all weight transposes, one compact launch
    prep_kernel<<<NTOK + TRN_BLOCKS, 256, 0, stream>>>(x, ln1w, ln1b, xn, jobs);
    // merged q|k|g + v^T projections, v3 geometry: 512 blocks = 2/CU, balanced
    proj_kernel<<<512, 256, 0, stream>>>(xn, qkgT, qkg, wvT, vT);
    // retention + groupnorm + silu gate: 1024 x 256, 4 blocks/CU, balanced
    retention_mfma<<<1024, 256, 0, stream>>>(qkg, vT, rg);
    // wo projection + residual x -> out (fp32); 512 blocks co-resident
    gemm_n64<1><<<dim3(32, 16), 256, 0, stream>>>(rg, D_MODEL, woT, nullptr, x, D_MODEL, out, D_MODEL, D_MODEL);
    // LN2 -> bf16
    ln_kernel<<<NTOK, 256, 0, stream>>>(out, ln2w, ln2b, xn, 1e-5f);
    // fused SwiGLU-in GEMM v3: row-tile-fastest grid (proven fastest)
    mlp_fused<<<dim3(NTOK / 256, HID_PAD / 64), 256, 0, stream>>>(xn, w_inT, b_in, hm);
    // w_out GEMM + bias + residual; 512 blocks co-resident
    gemm_n64<2><<<dim3(32, 16), 256, 0, stream>>>(hm, HID_PAD, w_outT, b_out, out, D_MODEL, out, D_MODEL, HID_PAD);
}

// Round 10
// 371.487 us; speedup vs baseline: 1.0150x; 1.0150x over previous
//
#include <hip/hip_runtime.h>
#include <math.h>

#define D_MODEL 1024
#define NHEAD   16
#define HDIM    64
#define HID     2730
#define HID_PAD 2816          // 22 * 128
#define SEQ     2048
#define BATCH   2
#define NTOK    (BATCH * SEQ)   // 4096
#define QKG     3072            // packed q|k|g row stride (elements)

typedef __attribute__((ext_vector_type(8))) short bf16x8;
typedef __attribute__((ext_vector_type(4))) float f32x4;
typedef __attribute__((ext_vector_type(4))) short s16x4;

// fp32 -> bf16 round-to-nearest-even
static __device__ inline short f2bf(float f)
{
    union { float f; unsigned int u; } c; c.f = f;
    unsigned int r = c.u + 0x7FFFu + ((c.u >> 16) & 1u);
    return (short)(r >> 16);
}
static __device__ inline float bf2f(short s)
{
    union { unsigned int u; float f; } c;
    c.u = ((unsigned int)(unsigned short)s) << 16;
    return c.f;
}

// fast silu denominator: 1/(1+e^-x) via v_exp + v_rcp (1-ulp; output goes
// through bf16 rounding anyway). Endpoints: x->-inf => rcp(inf)=0; x->+inf => 1.
static __device__ inline float fast_sigmoid(float x)
{
    return __builtin_amdgcn_rcpf(1.0f + __expf(-x));
}

// async global->LDS, 16B per lane; lds dest = wave-uniform base + lane*16
#define GLD16(gsrc, ldst) \
    __builtin_amdgcn_global_load_lds((const __attribute__((address_space(1))) void*)(gsrc), \
                                     (__attribute__((address_space(3))) void*)(ldst), 16, 0, 0)

// ---------------------------------------------------------------------------
// LDS bank-conflict-free tile layout (T2):
//   logical tile [R rows][32 k-shorts] stored as [R/2][64] where row r, granule
//   q (8 shorts) lives at p = r % (R/2), g = ((r / (R/2)) * 4 + q) ^ (p & 7).
//   Staging: LDS dest stays LINEAR; per-lane GLOBAL source is inverse-permuted.
// ---------------------------------------------------------------------------

// ---------------------------------------------------------------------------
// LayerNorm: one block (256 threads) per row of 1024, fp32 in -> bf16 out
// ---------------------------------------------------------------------------
__global__ void ln_kernel(const float* __restrict__ x,
                          const float* __restrict__ w,
                          const float* __restrict__ b,
                          short* __restrict__ out,
                          float eps)
{
    int row = blockIdx.x;
    int t = threadIdx.x;               // 0..255
    const float4* xr = (const float4*)(x + (size_t)row * D_MODEL);
    float4 v = xr[t];
    float s  = v.x + v.y + v.z + v.w;
    float sq = v.x * v.x + v.y * v.y + v.z * v.z + v.w * v.w;
#pragma unroll
    for (int off = 32; off > 0; off >>= 1) {
        s  += __shfl_xor(s, off);
        sq += __shfl_xor(sq, off);
    }
    __shared__ float ss[4], ssq[4];
    int wave = t >> 6;
    if ((t & 63) == 0) { ss[wave] = s; ssq[wave] = sq; }
    __syncthreads();
    s  = ss[0] + ss[1] + ss[2] + ss[3];
    sq = ssq[0] + ssq[1] + ssq[2] + ssq[3];
    float mu  = s * (1.0f / D_MODEL);
    float var = sq * (1.0f / D_MODEL) - mu * mu;
    float inv = rsqrtf(var + eps);
    float4 wv = ((const float4*)w)[t];
    float4 bv = ((const float4*)b)[t];
    s16x4 o;
    o.x = f2bf((v.x - mu) * inv * wv.x + bv.x);
    o.y = f2bf((v.y - mu) * inv * wv.y + bv.y);
    o.z = f2bf((v.z - mu) * inv * wv.z + bv.z);
    o.w = f2bf((v.w - mu) * inv * wv.w + bv.w);
    *(s16x4*)(out + (size_t)row * D_MODEL + 4 * t) = o;
}

// ---------------------------------------------------------------------------
// Transpose job table
// ---------------------------------------------------------------------------
struct TJob {
    const float* src;
    short* dst;
    int ldsrc, coloff, nvalid, kvalid, KPAD, NPAD;
};
struct TJobs { TJob j[8]; };

// ---------------------------------------------------------------------------
// prep_kernel: LN1 (blocks 0..NTOK-1) + ALL weight transposes (compact grid).
// ---------------------------------------------------------------------------
#define TRN_BLOCKS 3392

__global__ __launch_bounds__(256) void prep_kernel(
        const float* __restrict__ x,
        const float* __restrict__ ln1w,
        const float* __restrict__ ln1b,
        short* __restrict__ xn,
        TJobs jobs)
{
    __shared__ float tile[64][65];
    __shared__ float ss[4], ssq[4];
    int bid = blockIdx.x;
    int t = threadIdx.x;

    if (bid < NTOK) {
        // ---- LN1 row ----
        int row = bid;
        const float4* xr = (const float4*)(x + (size_t)row * D_MODEL);
        float4 v = xr[t];
        float s  = v.x + v.y + v.z + v.w;
        float sq = v.x * v.x + v.y * v.y + v.z * v.z + v.w * v.w;
#pragma unroll
        for (int off = 32; off > 0; off >>= 1) {
            s  += __shfl_xor(s, off);
            sq += __shfl_xor(sq, off);
        }
        int wave = t >> 6;
        if ((t & 63) == 0) { ss[wave] = s; ssq[wave] = sq; }
        __syncthreads();
        s  = ss[0] + ss[1] + ss[2] + ss[3];
        sq = ssq[0] + ssq[1] + ssq[2] + ssq[3];
        float mu  = s * (1.0f / D_MODEL);
        float var = sq * (1.0f / D_MODEL) - mu * mu;
        float inv = rsqrtf(var + 1e-5f);
        float4 wv = ((const float4*)ln1w)[t];
        float4 bv = ((const float4*)ln1b)[t];
        s16x4 o;
        o.x = f2bf((v.x - mu) * inv * wv.x + bv.x);
        o.y = f2bf((v.y - mu) * inv * wv.y + bv.y);
        o.z = f2bf((v.z - mu) * inv * wv.z + bv.z);
        o.w = f2bf((v.w - mu) * inv * wv.w + bv.w);
        *(s16x4*)(xn + (size_t)row * D_MODEL + 4 * t) = o;
        return;
    }

    // ---- transpose job ----
    int local = bid - NTOK;
    int jbi, kt, nt;
    if (local < 1280) {                 // jobs 0-4: 16x16
        jbi = local >> 8;
        int l = local & 255;
        kt = l & 15; nt = l >> 4;
    } else if (local < 2688) {          // jobs 5,6: 16k x 44n
        int l2 = local - 1280;
        jbi = 5 + (l2 >= 704 ? 1 : 0);
        int l3 = (l2 >= 704) ? l2 - 704 : l2;
        kt = l3 & 15; nt = l3 >> 4;
    } else {                            // job 7: 44k x 16n
        int l4 = local - 2688;
        jbi = 7;
        kt = l4 % 44; nt = l4 / 44;
    }
    TJob jb = jobs.j[jbi];
    int k0 = kt * 64, n0 = nt * 64;
    {
        int kk = t >> 2, np = (t & 3) << 4;
        int k = k0 + kk;
        bool kok = k < jb.kvalid;
        const float* srow = jb.src + (size_t)k * jb.ldsrc + jb.coloff + n0 + np;
#pragma unroll
        for (int i = 0; i < 16; ++i) {
            int n = n0 + np + i;
            tile[kk][np + i] = (kok && n < jb.nvalid) ? srow[i] : 0.0f;
        }
    }
    __syncthreads();
    {
        int nn = t >> 2, kp = (t & 3) << 4;
        short* drow = jb.dst + (size_t)(n0 + nn) * jb.KPAD + k0 + kp;
#pragma unroll
        for (int v4 = 0; v4 < 4; ++v4) {
            s16x4 o;
            o.x = f2bf(tile[kp + v4 * 4 + 0][nn]);
            o.y = f2bf(tile[kp + v4 * 4 + 1][nn]);
            o.z = f2bf(tile[kp + v4 * 4 + 2][nn]);
            o.w = f2bf(tile[kp + v4 * 4 + 3][nn]);
            *(s16x4*)(drow + v4 * 4) = o;
        }
    }
}

// ---------------------------------------------------------------------------
// proj v3: 256 rows x 128 out-cols per block, 4 waves, wave-tile 128x64,
// BK=32 dbuf gload_lds, T2-swizzled LDS. 512 blocks = 2/CU, balanced.
// ---------------------------------------------------------------------------
__global__ __launch_bounds__(256, 2) void proj_kernel(
        const short* __restrict__ xn,
        const short* __restrict__ qkgT,
        short* __restrict__ qkg,
        const short* __restrict__ wvT,
        short* __restrict__ vT)
{
    __shared__ short As[2][8192];          // 256 r x 32 k (swizzled)
    __shared__ short Bs[2][4096];          // 128 n x 32 k (swizzled)
    const int K = D_MODEL;
    int id = blockIdx.x;
    const short *A, *Bt;
    short* C;
    int ldc, bm, bn;
    if (id < 384) {                        // xn @ qkgT^T -> qkg
        A = xn; Bt = qkgT; C = qkg; ldc = QKG;
        bm = (id & 15) * 256; bn = (id >> 4) * 128;
    } else {                               // wvT @ xn^T -> vT
        int i2 = id - 384;
        A = wvT; Bt = xn; C = vT; ldc = NTOK;
        bm = (i2 & 3) * 256; bn = (i2 >> 2) * 128;
    }

    int t = threadIdx.x;
    int w = t >> 6;
    int lane = t & 63;
    int quad = lane >> 4;
    int l15  = lane & 15;
    int x7   = l15 & 7;

    int li3 = lane >> 3;
    int u   = (lane & 7) ^ li3;
    int hi  = u >> 2;
    int qk  = (u & 3) << 3;
    const short* gA = A + (size_t)(bm + hi * 128 + w * 32 + li3) * K + qk;
    const short* gB = Bt + (size_t)(bn + hi * 64 + w * 16 + li3) * K + qk;

    int abase = l15 * 64 + ((((w >> 1) << 2) | quad) ^ x7) * 8;
    int bbase = l15 * 64 + ((((w & 1) << 2) | quad) ^ x7) * 8;

    f32x4 acc[8][4];
#pragma unroll
    for (int i = 0; i < 8; ++i)
#pragma unroll
        for (int j = 0; j < 4; ++j) acc[i][j] = (f32x4){0.f, 0.f, 0.f, 0.f};

#pragma unroll
    for (int c = 0; c < 4; ++c)
        GLD16(gA + (size_t)c * 8 * K, &As[0][w * 2048 + c * 512]);
#pragma unroll
    for (int c = 0; c < 2; ++c)
        GLD16(gB + (size_t)c * 8 * K, &Bs[0][w * 1024 + c * 512]);

    for (int k0 = 0; k0 < K; k0 += 32) {
        int cur = (k0 >> 5) & 1;
        __syncthreads();
        int k1 = k0 + 32;
        if (k1 < K) {
#pragma unroll
            for (int c = 0; c < 4; ++c)
                GLD16(gA + (size_t)c * 8 * K + k1, &As[cur ^ 1][w * 2048 + c * 512]);
#pragma unroll
            for (int c = 0; c < 2; ++c)
                GLD16(gB + (size_t)c * 8 * K + k1, &Bs[cur ^ 1][w * 1024 + c * 512]);
        }
        bf16x8 af[8], bfr[4];
#pragma unroll
        for (int m = 0; m < 8; ++m)
            af[m] = *(const bf16x8*)(&As[cur][m * 1024 + abase]);
#pragma unroll
        for (int jf = 0; jf < 4; ++jf)
            bfr[jf] = *(const bf16x8*)(&Bs[cur][jf * 1024 + bbase]);
#pragma unroll
        for (int m = 0; m < 8; ++m)
#pragma unroll
            for (int jf = 0; jf < 4; ++jf)
                acc[m][jf] = __builtin_amdgcn_mfma_f32_16x16x32_bf16(af[m], bfr[jf], acc[m][jf], 0, 0, 0);
    }

#pragma unroll
    for (int m = 0; m < 8; ++m) {
        int gr = bm + (w >> 1) * 128 + m * 16 + quad * 4;
#pragma unroll
        for (int jf = 0; jf < 4; ++jf) {
            int gc = bn + (w & 1) * 64 + jf * 16 + l15;
#pragma unroll
            for (int r = 0; r < 4; ++r)
                C[(size_t)(gr + r) * ldc + gc] = f2bf(acc[m][jf][r]);
        }
    }
}

// ---------------------------------------------------------------------------
// 128x64-tile GEMM for the N=1024 projections (wo, w_out): 512 blocks
// co-resident (4/CU); T2-swizzled LDS.
// ---------------------------------------------------------------------------
template<int EPI>
__global__ __launch_bounds__(256, 4) void gemm_n64(
        const short* __restrict__ A, int lda,
        const short* __restrict__ Bt,
        const float* __restrict__ bias,
        const float* __restrict__ R, int ldr,
        void* __restrict__ C, int ldc, int K)
{
    __shared__ short As[2][4096];
    __shared__ short Bs[2][2048];
    int bm = blockIdx.x * 128;          // row tile fastest
    int bn = blockIdx.y * 64;
    int t = threadIdx.x;
    int w = t >> 6;
    int lane = t & 63;
    int quad = lane >> 4;
    int l15  = lane & 15;
    int x7   = l15 & 7;

    int p0 = t >> 3;
    int u  = (t & 7) ^ (p0 & 7);
    int scol = (u & 3) << 3;
    const short* gA0 = A  + (size_t)(bm + p0 + ((u >> 2) << 6)) * lda + scol;
    const short* gA1 = gA0 + (size_t)32 * lda;
    const short* gB0 = Bt + (size_t)(bn + p0 + ((u >> 2) << 5)) * K + scol;  // 64-row tile: hi<<5
    int wb = w << 9;

    int wr = (w >> 1) * 64;
    int wc = (w & 1) * 32;
    int aoff = l15 * 64 + (((((w >> 1) << 2) | quad) ^ x7) << 3);
    int boff = l15 * 64 + (((((w & 1) << 2) | quad) ^ x7) << 3);

    f32x4 acc[4][2];
#pragma unroll
    for (int i = 0; i < 4; ++i)
#pragma unroll
        for (int j = 0; j < 2; ++j) acc[i][j] = (f32x4){0.f, 0.f, 0.f, 0.f};

    GLD16(gA0, &As[0][wb]);
    GLD16(gA1, &As[0][2048 + wb]);
    GLD16(gB0, &Bs[0][wb]);

    for (int k0 = 0; k0 < K; k0 += 32) {
        int cur = (k0 >> 5) & 1;
        __syncthreads();
        int k1 = k0 + 32;
        if (k1 < K) {
            GLD16(gA0 + k1, &As[cur ^ 1][wb]);
            GLD16(gA1 + k1, &As[cur ^ 1][2048 + wb]);
            GLD16(gB0 + k1, &Bs[cur ^ 1][wb]);
        }
        bf16x8 af[4], bfr[2];
#pragma unroll
        for (int i = 0; i < 4; ++i)
            af[i] = *(const bf16x8*)(&As[cur][i * 1024 + aoff]);
#pragma unroll
        for (int j = 0; j < 2; ++j)
            bfr[j] = *(const bf16x8*)(&Bs[cur][j * 1024 + boff]);
#pragma unroll
        for (int i = 0; i < 4; ++i)
#pragma unroll
            for (int j = 0; j < 2; ++j)
                acc[i][j] = __builtin_amdgcn_mfma_f32_16x16x32_bf16(af[i], bfr[j], acc[i][j], 0, 0, 0);
    }

#pragma unroll
    for (int i = 0; i < 4; ++i) {
        int gr = bm + wr + i * 16 + quad * 4;
#pragma unroll
        for (int j = 0; j < 2; ++j) {
            int gc = bn + wc + j * 16 + l15;
#pragma unroll
            for (int r = 0; r < 4; ++r) {
                float val = acc[i][j][r];
                size_t idx = (size_t)(gr + r) * ldc + gc;
                if (EPI == 0) {
                    ((short*)C)[idx] = f2bf(val);
                } else if (EPI == 1) {
                    ((float*)C)[idx] = val + R[(size_t)(gr + r) * ldr + gc];
                } else {
                    ((float*)C)[idx] = val + bias[gc] + R[(size_t)(gr + r) * ldr + gc];
                }
            }
        }
    }
}

// ---------------------------------------------------------------------------
// Fused SwiGLU-in GEMM v3: block 256 rows x 64 out-cols (128 a|b-interleaved
// weight rows), 4 waves with 128x64 wave-tiles, BK=32, 2-phase dbuf
// gload_lds, T2-swizzled LDS. Row-tile-fastest grid (proven fastest, r5).
// 2 blocks/CU (register-limited). Epilogue: silu via v_exp+v_rcp (no IEEE div).
// ---------------------------------------------------------------------------
__global__ __launch_bounds__(256, 2) void mlp_fused(
        const short* __restrict__ A,       // [NTOK][1024] bf16
        const short* __restrict__ w_inT,   // [2*HID_PAD][1024] bf16
        const float* __restrict__ b_in,    // [2*HID]
        short* __restrict__ hm)            // [NTOK][HID_PAD] bf16
{
    __shared__ short As[2][8192];          // 32 KB
    __shared__ short Bs[2][4096];          // 16 KB
    const int K = D_MODEL;
    int bm = blockIdx.x * 256;             // row tile fastest (16)
    int bn = blockIdx.y * 64;              // out-col tile (44)
    int t = threadIdx.x;
    int w = t >> 6;
    int lane = t & 63;
    int quad = lane >> 4;
    int l15  = lane & 15;
    int x7   = l15 & 7;

    int li3 = lane >> 3;
    int u   = (lane & 7) ^ li3;
    int hi  = u >> 2;
    int qk  = (u & 3) << 3;
    const short* gA = A + (size_t)(bm + hi * 128 + w * 32 + li3) * K + qk;
    int f = hi * 4 + w;
    const short* gB = w_inT + (size_t)(((f & 1) ? HID_PAD : 0) + bn
                                       + ((f >> 1) << 4) + li3) * K + qk;

    int abase = l15 * 64 + ((((w >> 1) << 2) | quad) ^ x7) * 8;
    int bbase = l15 * 64 + ((((w & 1) << 2) | quad) ^ x7) * 8;

    f32x4 acc[8][4];
#pragma unroll
    for (int i = 0; i < 8; ++i)
#pragma unroll
        for (int j = 0; j < 4; ++j) acc[i][j] = (f32x4){0.f, 0.f, 0.f, 0.f};

#pragma unroll
    for (int c = 0; c < 4; ++c)
        GLD16(gA + (size_t)c * 8 * K, &As[0][w * 2048 + c * 512]);
#pragma unroll
    for (int c = 0; c < 2; ++c)
        GLD16(gB + (size_t)c * 8 * K, &Bs[0][w * 1024 + c * 512]);

    for (int k0 = 0; k0 < K; k0 += 32) {
        int cur = (k0 >> 5) & 1;
        __syncthreads();
        int k1 = k0 + 32;
        if (k1 < K) {
#pragma unroll
            for (int c = 0; c < 4; ++c)
                GLD16(gA + (size_t)c * 8 * K + k1, &As[cur ^ 1][w * 2048 + c * 512]);
#pragma unroll
            for (int c = 0; c < 2; ++c)
                GLD16(gB + (size_t)c * 8 * K + k1, &Bs[cur ^ 1][w * 1024 + c * 512]);
        }
        bf16x8 af[8], bfr[4];
#pragma unroll
        for (int m = 0; m < 8; ++m)
            af[m] = *(const bf16x8*)(&As[cur][m * 1024 + abase]);
#pragma unroll
        for (int jf = 0; jf < 4; ++jf)
            bfr[jf] = *(const bf16x8*)(&Bs[cur][jf * 1024 + bbase]);
#pragma unroll
        for (int m = 0; m < 8; ++m)
#pragma unroll
            for (int jf = 0; jf < 4; ++jf)
                acc[m][jf] = __builtin_amdgcn_mfma_f32_16x16x32_bf16(af[m], bfr[jf], acc[m][jf], 0, 0, 0);
    }

#pragma unroll
    for (int m = 0; m < 8; ++m) {
        int gr = bm + (w >> 1) * 128 + m * 16 + quad * 4;
#pragma unroll
        for (int jj = 0; jj < 2; ++jj) {
            int gc = bn + (((w & 1) << 1) + jj) * 16 + l15;
            bool ok = gc < HID;
            float ba = ok ? b_in[gc] : 0.0f;
            float bb = ok ? b_in[HID + gc] : 0.0f;
#pragma unroll
            for (int r = 0; r < 4; ++r) {
                float a  = acc[m][2 * jj][r] + ba;
                float bv = acc[m][2 * jj + 1][r] + bb;
                float val = ok ? a * bv * fast_sigmoid(bv) : 0.0f;
                hm[(size_t)(gr + r) * HID_PAD + gc] = f2bf(val);
            }
        }
    }
}

// ---------------------------------------------------------------------------
// MFMA retention + groupnorm + silu gate, v3 + VALU trim:
//   - 64-row q-blocks: grid 1024 x 256 threads (4 waves x 16 rows), 4 blk/CU.
//   - P conversion via v_cvt_pk_bf16_f32 (2 f32 -> 1 instr, RNE) instead of
//     manual f2bf (3 instr/value): -32 VALU per wave tile-step in hot loop.
//   - gate silu via v_exp+v_rcp (no IEEE div sequence).
//   - addresses/layout identical to the r9-verified kernel.
// ---------------------------------------------------------------------------
#define PSH 36   // half-P row stride in shorts (>=32, bank-spread)

__global__ __launch_bounds__(256) void retention_mfma(
        const short* __restrict__ qkg,
        const short* __restrict__ vT,
        short* __restrict__ rg)
{
    int i  = blockIdx.x;                 // 0..1023
    int h  = i & 15;
    int t5 = i >> 4;                     // 0..63
    int b  = t5 >> 5;
    int m  = t5 & 31;
    int j  = b ? m : 31 - m;             // 64-row q-block index (0..31)

    __shared__ short ks[2][4096];        // [buf][d-chunk(2)][32][64] swizzled
    __shared__ short vt[2][4096];        // [buf][t-chunk(2)][32][64] swizzled
    __shared__ short ps[4][16 * PSH];    // per-wave HALF P (16 q x 32 t)

    int tid  = threadIdx.x;
    int w    = tid >> 6;                 // 0..3
    int lane = tid & 63;
    int quad = lane >> 4;
    int l15  = lane & 15;
    int x7   = l15 & 7;

    float log2g = log1pf(-exp2f(-5.0f - (float)h)) * 1.4426950408889634f;
    int hcol = h * HDIM;
    int s0 = j * 64;
    size_t tok0 = (size_t)b * SEQ;

    // swizzled staging source: dest slot (p = tid>>3, g = tid&7); chunk explicit
    int p0 = tid >> 3;                   // 0..31
    int g  = tid & 7;
    int ur = g ^ (p0 & 7);
    int srw = p0 + ((ur >> 2) << 5);     // row within 64-row tile
    int sc8 = (ur & 3) << 3;
    const short* kbase = qkg + (tok0 + srw) * QKG + 1024 + hcol + sc8;
    const short* vbase = vT + (size_t)(hcol + srw) * NTOK + tok0 + sc8;
    int lb = tid << 3;                   // 0..2047 (shorts within chunk)

    const short* qrow = qkg + (tok0 + s0 + w * 16 + l15) * QKG + hcol;
    bf16x8 qa0 = *(const bf16x8*)(qrow + quad * 8);
    bf16x8 qa1 = *(const bf16x8*)(qrow + 32 + quad * 8);

    float colfac[4];
#pragma unroll
    for (int tile = 0; tile < 4; ++tile)
        colfac[tile] = exp2f(-(float)(tile * 16 + l15) * log2g) * 0.125f;

    f32x4 oacc[4];
#pragma unroll
    for (int k = 0; k < 4; ++k) oacc[k] = (f32x4){0.f, 0.f, 0.f, 0.f};

    int sbase = s0 + w * 16 + quad * 4;
    int tmax = j;                        // tiles 0..j

    // row decay recurrence (proven r7): rf0 = gamma^(sbase+reg), *= gamma^-64
    float rf[4];
#pragma unroll
    for (int reg = 0; reg < 4; ++reg)
        rf[reg] = exp2f((float)(sbase + reg) * log2g);
    float gstep = exp2f(-64.0f * log2g);

    GLD16(kbase,      &ks[0][lb]);
    GLD16(kbase + 32, &ks[0][2048 + lb]);
    GLD16(vbase,      &vt[0][lb]);
    GLD16(vbase + 32, &vt[0][2048 + lb]);

    for (int tb = 0; tb <= tmax; ++tb) {
        int cur = tb & 1;
        __syncthreads();
        if (tb < tmax) {
            size_t ko = (size_t)(tb + 1) * 64 * QKG;
            int    vo = (tb + 1) * 64;
            GLD16(kbase + ko,      &ks[cur ^ 1][lb]);
            GLD16(kbase + ko + 32, &ks[cur ^ 1][2048 + lb]);
            GLD16(vbase + vo,      &vt[cur ^ 1][lb]);
            GLD16(vbase + vo + 32, &vt[cur ^ 1][2048 + lb]);
        }

        f32x4 sacc[4];
#pragma unroll
        for (int k = 0; k < 4; ++k) sacc[k] = (f32x4){0.f, 0.f, 0.f, 0.f};
#pragma unroll
        for (int tile = 0; tile < 4; ++tile) {
            int kaddr = ((tile & 1) * 16 + l15) * 64 +
                        (((((tile >> 1) << 2) | quad) ^ x7) << 3);
            bf16x8 kb0 = *(const bf16x8*)(&ks[cur][kaddr]);
            bf16x8 kb1 = *(const bf16x8*)(&ks[cur][2048 + kaddr]);
            sacc[tile] = __builtin_amdgcn_mfma_f32_16x16x32_bf16(qa0, kb0, sacc[tile], 0, 0, 0);
            sacc[tile] = __builtin_amdgcn_mfma_f32_16x16x32_bf16(qa1, kb1, sacc[tile], 0, 0, 0);
        }

        int fbi = sbase - tb * 64;
        bool needmask = (tb * 64 + 63 > s0 + w * 16);

#pragma unroll
        for (int ksi = 0; ksi < 2; ++ksi) {
            // ---- store half-P (tiles 2ksi, 2ksi+1), pk-converted ----
#pragma unroll
            for (int th = 0; th < 2; ++th) {
                int tile = ksi * 2 + th;
                int tt = tile * 16 + l15;
                float pv0, pv1, pv2, pv3;
                if (needmask) {
                    pv0 = (fbi + 0 >= tt) ? sacc[tile][0] * rf[0] * colfac[tile] : 0.0f;
                    pv1 = (fbi + 1 >= tt) ? sacc[tile][1] * rf[1] * colfac[tile] : 0.0f;
                    pv2 = (fbi + 2 >= tt) ? sacc[tile][2] * rf[2] * colfac[tile] : 0.0f;
                    pv3 = (fbi + 3 >= tt) ? sacc[tile][3] * rf[3] * colfac[tile] : 0.0f;
                } else {
                    pv0 = sacc[tile][0] * (rf[0] * colfac[tile]);
                    pv1 = sacc[tile][1] * (rf[1] * colfac[tile]);
                    pv2 = sacc[tile][2] * (rf[2] * colfac[tile]);
                    pv3 = sacc[tile][3] * (rf[3] * colfac[tile]);
                }
                unsigned w01, w23;
                asm("v_cvt_pk_bf16_f32 %0, %1, %2" : "=v"(w01) : "v"(pv0), "v"(pv1));
                asm("v_cvt_pk_bf16_f32 %0, %1, %2" : "=v"(w23) : "v"(pv2), "v"(pv3));
                short* pb = &ps[w][(quad * 4) * PSH + th * 16 + l15];
                pb[0]       = (short)(w01 & 0xffffu);
                pb[PSH]     = (short)(w01 >> 16);
                pb[2 * PSH] = (short)(w23 & 0xffffu);
                pb[3 * PSH] = (short)(w23 >> 16);
            }
            // ---- PV with this half (wave-local LDS, in-order per wave) ----
            bf16x8 pa = *(const bf16x8*)(&ps[w][l15 * PSH + quad * 8]);
#pragma unroll
            for (int dt = 0; dt < 4; ++dt) {
                int vaddr = ((dt & 1) * 16 + l15) * 64 +
                            (((((dt >> 1) << 2) | quad) ^ x7) << 3);
                bf16x8 vb = *(const bf16x8*)(&vt[cur][ksi * 2048 + vaddr]);
                oacc[dt] = __builtin_amdgcn_mfma_f32_16x16x32_bf16(pa, vb, oacc[dt], 0, 0, 0);
            }
        }
#pragma unroll
        for (int reg = 0; reg < 4; ++reg)
            rf[reg] *= gstep;
    }

    float s1[4], s2[4];
#pragma unroll
    for (int reg = 0; reg < 4; ++reg) {
        s1[reg] = oacc[0][reg] + oacc[1][reg] + oacc[2][reg] + oacc[3][reg];
        s2[reg] = oacc[0][reg] * oacc[0][reg] + oacc[1][reg] * oacc[1][reg]
                + oacc[2][reg] * oacc[2][reg] + oacc[3][reg] * oacc[3][reg];
    }
#pragma unroll
    for (int off = 1; off < 16; off <<= 1) {
#pragma unroll
        for (int reg = 0; reg < 4; ++reg) {
            s1[reg] += __shfl_xor(s1[reg], off);
            s2[reg] += __shfl_xor(s2[reg], off);
        }
    }
    size_t rowtok = tok0 + s0 + w * 16 + quad * 4;
    short* obase = rg + rowtok * D_MODEL + hcol;
    const short* gbase = qkg + rowtok * QKG + 2048 + hcol;
#pragma unroll
    for (int reg = 0; reg < 4; ++reg) {
        float mu  = s1[reg] * (1.0f / 64.0f);
        float var = s2[reg] * (1.0f / 64.0f) - mu * mu;
        float inv = rsqrtf(var + 1e-6f);
#pragma unroll
        for (int dt = 0; dt < 4; ++dt) {
            float gv = bf2f(gbase[(size_t)reg * QKG + dt * 16 + l15]);
            float val = (oacc[dt][reg] - mu) * inv * (gv * fast_sigmoid(gv));
            obase[(size_t)reg * D_MODEL + dt * 16 + l15] = f2bf(val);
        }
    }
}

// ---------------------------------------------------------------------------
extern "C" void kernel_launch(void* const* d_in, const int* in_sizes, int n_in,
                              void* d_out, int out_size, void* d_ws, size_t ws_size,
                              hipStream_t stream)
{
    const float* x     = (const float*)d_in[0];
    const float* ln1w  = (const float*)d_in[1];
    const float* ln1b  = (const float*)d_in[2];
    const float* wq    = (const float*)d_in[3];
    const float* wk    = (const float*)d_in[4];
    const float* wv    = (const float*)d_in[5];
    const float* wg    = (const float*)d_in[6];
    const float* wo    = (const float*)d_in[7];
    const float* ln2w  = (const float*)d_in[8];
    const float* ln2b  = (const float*)d_in[9];
    const float* w_in  = (const float*)d_in[10];
    const float* b_in  = (const float*)d_in[11];
    const float* w_out = (const float*)d_in[12];
    const float* b_out = (const float*)d_in[13];
    float* out = (float*)d_out;
    char* base = (char*)d_ws;

    const size_t MB = 1u << 20;
    short* xn     = (short*)(base);            // [0,8)   [4096][1024] bf16 LN out
    short* qkgT   = (short*)(base +  8 * MB);  // [8,14)  wq|wk|wg transposed [3072][1024]
    short* wvT    = (short*)(base + 14 * MB);  // [14,16) [1024][1024]
    short* woT    = (short*)(base + 16 * MB);  // [16,18) [1024][1024]
    short* w_inT  = (short*)(base + 18 * MB);  // [18,29) [5632][1024]
    short* w_outT = (short*)(base + 29 * MB);  // [29,34.5) [1024][2816]
    short* qkg    = (short*)(base + 35 * MB);  // [35,59) [4096][3072] packed q|k|g
    short* hm     = (short*)(base + 35 * MB);  // [35,57) [4096][2816] reuses dead qkg
    short* vT     = (short*)(base + 59 * MB);  // [59,67) [1024][4096] V transposed
    short* rg     = (short*)(base + 67 * MB);  // [67,75) [4096][1024] gated retention out

    TJobs jobs;
    jobs.j[0] = { wq,    qkgT,                          1024,    0, 1024, 1024, 1024, 1024 };
    jobs.j[1] = { wk,    qkgT + 1024 * 1024,            1024,    0, 1024, 1024, 1024, 1024 };
    jobs.j[2] = { wg,    qkgT + 2 * 1024 * 1024,        1024,    0, 1024, 1024, 1024, 1024 };
    jobs.j[3] = { wv,    wvT,                           1024,    0, 1024, 1024, 1024, 1024 };
    jobs.j[4] = { wo,    woT,                           1024,    0, 1024, 1024, 1024, 1024 };
    jobs.j[5] = { w_in,  w_inT,                         2 * HID, 0,   HID, 1024, 1024, HID_PAD };
    jobs.j[6] = { w_in,  w_inT + (size_t)HID_PAD * 1024, 2 * HID, HID, HID, 1024, 1024, HID_PAD };
    jobs.j[7] = { w_out, w_outT,                        1024,    0, 1024, HID, HID_PAD, 1024 };

    // LN1 + all weight transposes, one compact launch
    prep_kernel<<<NTOK + TRN_BLOCKS, 256, 0, stream>>>(x, ln1w, ln1b, xn, jobs);
    // merged q|k|g + v^T projections, v3 geometry: 512 blocks = 2/CU, balanced
    proj_kernel<<<512, 256, 0, stream>>>(xn, qkgT, qkg, wvT, vT);
    // retention + groupnorm + silu gate: 1024 x 256, 4 blocks/CU, balanced
    retention_mfma<<<1024, 256, 0, stream>>>(qkg, vT, rg);
    // wo projection + residual x -> out (fp32); 512 blocks co-resident
    gemm_n64<1><<<dim3(32, 16), 256, 0, stream>>>(rg, D_MODEL, woT, nullptr, x, D_MODEL, out, D_MODEL, D_MODEL);
    // LN2 -> bf16
    ln_kernel<<<NTOK, 256, 0, stream>>>(out, ln2w, ln2b, xn, 1e-5f);
    // fused SwiGLU-in GEMM v3: row-tile-fastest grid (proven fastest)
    mlp_fused<<<dim3(NTOK / 256, HID_PAD / 64), 256, 0, stream>>>(xn, w_inT, b_in, hm);
    // w_out GEMM + bias + residual; 512 blocks co-resident
    gemm_n64<2><<<dim3(32, 16), 256, 0, stream>>>(hm, HID_PAD, w_outT, b_out, out, D_MODEL, out, D_MODEL, HID_PAD);
}